// Round 3
// baseline (100.658 us; speedup 1.0000x reference)
//
#include <hip/hip_runtime.h>
#include <hip/hip_bf16.h>

typedef __attribute__((ext_vector_type(8))) short short8;
typedef __attribute__((ext_vector_type(4))) float float4v;
typedef __attribute__((ext_vector_type(16))) float f32x16;

__device__ __forceinline__ unsigned short f2bf(float f) {
    // round-to-nearest-even fp32 -> bf16
    unsigned int u = __builtin_bit_cast(unsigned int, f);
    unsigned int lsb = (u >> 16) & 1u;
    u += 0x7fffu + lsb;
    return (unsigned short)(u >> 16);
}

__device__ __forceinline__ unsigned int pack2(float f0, float f1) {
    // round-half-up fp32x2 -> packed bf16x2
    unsigned int u0 = __builtin_bit_cast(unsigned int, f0) + 0x8000u;
    unsigned int u1 = __builtin_bit_cast(unsigned int, f1) + 0x8000u;
    return (u0 >> 16) | (u1 & 0xffff0000u);
}

// ---------------------------------------------------------------------------
// prep (unchanged from v10): LN + projections (MFMA) and woT build.
// b stored plain as b3[octet o][R=global b-row][8]: fused's 32x32 producer
// B-loads are two contiguous 512B blocks per instruction.
// ---------------------------------------------------------------------------
__global__ __launch_bounds__(128) void prep(
    const float* __restrict__ msa, const float* __restrict__ ln_w,
    const float* __restrict__ ln_b, const float* __restrict__ wa,
    const float* __restrict__ ba, const float* __restrict__ wb,
    const float* __restrict__ bb, const float* __restrict__ wo,
    unsigned short* __restrict__ a_out, unsigned short* __restrict__ b_out,
    unsigned short* __restrict__ woT)
{
    const int b = blockIdx.x;
    if (b >= 512) {                       // ---- woT transpose/convert ----
        const int idx = (b - 512) * 128 + threadIdx.x;
        const int hk = idx >> 6, p = idx & 63;
        const int h = hk >> 5, k = hk & 31;
        woT[(size_t)p * 1024 + k * 32 + h] = f2bf(wo[idx]);
        return;
    }

    __shared__ __align__(16) unsigned short xn[2][16 * 72];
    const int n = b >> 1;
    const int w = threadIdx.x >> 6;
    const int lane = threadIdx.x & 63;
    const int s0 = (b & 1) * 32 + w * 16;
    const int sl = lane >> 2, dg = lane & 3;
    const int lm = lane & 15, q = lane >> 4;

    const float* __restrict__ row = msa + ((size_t)((s0 + sl) * 256 + n)) * 64;
    float4 x[4];
    #pragma unroll
    for (int ii = 0; ii < 4; ++ii) x[ii] = *(const float4*)(row + ii * 16 + dg * 4);

    float s = 0.f;
    #pragma unroll
    for (int ii = 0; ii < 4; ++ii) s += (x[ii].x + x[ii].y) + (x[ii].z + x[ii].w);
    s += __shfl_xor(s, 1, 4);
    s += __shfl_xor(s, 2, 4);
    const float mu = s * (1.f / 64.f);

    float v = 0.f;
    #pragma unroll
    for (int ii = 0; ii < 4; ++ii) {
        float a0 = x[ii].x - mu, a1 = x[ii].y - mu, a2 = x[ii].z - mu, a3 = x[ii].w - mu;
        v += (a0 * a0 + a1 * a1) + (a2 * a2 + a3 * a3);
    }
    v += __shfl_xor(v, 1, 4);
    v += __shfl_xor(v, 2, 4);
    const float rs = rsqrtf(v * (1.f / 64.f) + 1e-5f);

    #pragma unroll
    for (int ii = 0; ii < 4; ++ii) {
        const float4 lw = *(const float4*)(ln_w + ii * 16 + dg * 4);
        const float4 lb = *(const float4*)(ln_b + ii * 16 + dg * 4);
        uint2 pk;
        pk.x = pack2((x[ii].x - mu) * rs * lw.x + lb.x, (x[ii].y - mu) * rs * lw.y + lb.y);
        pk.y = pack2((x[ii].z - mu) * rs * lw.z + lb.z, (x[ii].w - mu) * rs * lw.w + lb.w);
        *(uint2*)(&xn[w][sl * 72 + ii * 16 + dg * 4]) = pk;
    }
    __syncthreads();

    short8 afr[2];
    #pragma unroll
    for (int ks = 0; ks < 2; ++ks)
        afr[ks] = *(const short8*)(&xn[w][lm * 72 + ks * 32 + q * 8]);

    float4v acc[4];
    #pragma unroll
    for (int c = 0; c < 4; ++c) acc[c] = (float4v){0.f, 0.f, 0.f, 0.f};
    #pragma unroll
    for (int c = 0; c < 4; ++c) {
        const int hp = c * 16 + lm;
        const float* __restrict__ wsrc = (hp < 32) ? (wa + hp) : (wb + hp - 32);
        #pragma unroll
        for (int ks = 0; ks < 2; ++ks) {
            short8 bfr;
            #pragma unroll
            for (int j = 0; j < 8; ++j)
                bfr[j] = (short)f2bf(wsrc[(ks * 32 + q * 8 + j) * 32]);
            acc[c] = __builtin_amdgcn_mfma_f32_16x16x32_bf16(afr[ks], bfr, acc[c], 0, 0, 0);
        }
    }

    #pragma unroll
    for (int c = 0; c < 4; ++c) {
        const int hp = c * 16 + lm;
        const float bias = (hp < 32) ? ba[hp] : bb[hp - 32];
        const float scale = (hp < 32) ? (1.f / 64.f) : 1.f;  // fold 1/S into a
        uint2 pk;
        pk.x = pack2((acc[c][0] + bias) * scale, (acc[c][1] + bias) * scale);
        pk.y = pack2((acc[c][2] + bias) * scale, (acc[c][3] + bias) * scale);
        const int sbase = s0 + q * 4;
        if (hp < 32) {
            *(uint2*)(a_out + ((size_t)(n * 32 + hp)) * 64 + sbase) = pk;
        } else {
            // b3[o][R][8]: o = s-octet, R = global b-row; uint2 = half an octet
            const int R = n * 32 + (hp - 32);
            const int o = sbase >> 3;
            *(uint2*)(b_out + (size_t)o * 65536 + R * 8 + (sbase & 7)) = pk;
        }
    }
}

// ---------------------------------------------------------------------------
// fused_opm v11: stage 2 moved to mfma_f32_32x32x16_bf16 (2-tile batched).
// v10 post-mortem: exact prediction hit -> critical path = per-SIMD serialized
// MFMA issue of producer+consumer wave pair: 516 (prod 32x32) + 621 (cons
// 16x16) = 1137 cyc/tile. Stage2 at 32x32 needs 32 B-cols, tile has 16 pairs
// -> batch TWO tiles: B cols = 16 pairs x 2 tiles (l31>>4 selects M buffer),
// K=16/MFMA over the wave's unchanged 256-elem (k,h) slice. 32 MFMAs per
// 2-tile batch per wave -> 516 cyc/tile; floor 516+516 = 1032 (-105/tile).
// Pipeline (v = 0..8, two barrier-slots each; t = 2v, 2v+1):
//   even slot t=2v : producers write tile 2v -> M[(2v)%3];
//                    consumers (v>=1) stage2(batch v-1): read M[(2v-2)%3],
//                    M[(2v-1)%3], write R.
//   odd slot t=2v+1: producers write tile 2v+1 -> M[(2v+1)%3];
//                    consumers (v>=1) reduce(batch v-1): read R, write out.
// Hazards: M buffer (2u)%3 holds tile 2u, read at t=2u+2 (even slot); next
// write of that buffer is tile 2u+3 at t=2u+3 — barrier-separated. R: write
// even slot, read next odd slot, next write one barrier later -> single
// buffer. LDS: M 3x39.75 + R 34 = 153.3 KB -> 1 block/CU (unchanged).
// LDS traffic/tile unchanged (M 32+32, R 16+16 KB); R stride 68 floats
// (p-dim 64 + 4 pad) -> conflict-free write/read (4-bank step per lane).
// ---------------------------------------------------------------------------
__global__ __launch_bounds__(512, 2) void fused_opm(
    const unsigned short* __restrict__ a_b, const unsigned short* __restrict__ b_swz,
    const unsigned short* __restrict__ woT, const float* __restrict__ bo,
    float* __restrict__ out)
{
    __shared__ __align__(16) unsigned short ldsM[3][16 * 1272]; // 119.25 KB
    __shared__ __align__(16) float ldsR[128 * 68];              // 34 KB

    const int b = blockIdx.x;
    const int bi = b >> 2;
    const int bj0 = (b & 3) << 4;        // 16 tiles per block
    const int wv = threadIdx.x >> 6;
    const int lane = threadIdx.x & 63;
    const int l31 = lane & 31, h5 = lane >> 5;

    if (wv < 4) {
        // ========= PRODUCERS: stage 1 (32x32x16, B from plain-layout global) =========
        const int w = wv;                 // B-row slice [32w, +32)

        short8 af[4][4];                  // [rf: row block][ks: s-step]
        #pragma unroll
        for (int rf = 0; rf < 4; ++rf)
            #pragma unroll
            for (int ks = 0; ks < 4; ++ks)
                af[rf][ks] = *(const short8*)(a_b + ((size_t)(bi * 128 + rf * 32 + l31)) * 64 + ks * 16 + h5 * 8);

        short8 bfA[4], bfB[4];            // register double-buffer, one tile ahead
        auto loadbf = [&](short8 (&dst)[4], int tt) {
            const int Rbase = (bj0 + tt) * 128 + w * 32 + l31;
            #pragma unroll
            for (int ks = 0; ks < 4; ++ks) {
                const int o = ks * 2 + h5;                // s-octet
                dst[ks] = *(const short8*)(b_swz + (size_t)o * 65536 + (size_t)Rbase * 8);
            }
        };
        auto step = [&](short8 (&cur)[4], short8 (&nxt)[4], int t, int mi) {
            if (t + 1 < 16) loadbf(nxt, t + 1);           // issue before MFMAs
            if (t < 16) {
                unsigned short* __restrict__ M = ldsM[mi];
                f32x16 acc1[4];
                #pragma unroll
                for (int rf = 0; rf < 4; ++rf)
                    #pragma unroll
                    for (int e = 0; e < 16; ++e) acc1[rf][e] = 0.f;
                #pragma unroll
                for (int ks = 0; ks < 4; ++ks)
                    #pragma unroll
                    for (int rf = 0; rf < 4; ++rf)
                        acc1[rf] = __builtin_amdgcn_mfma_f32_32x32x16_bf16(af[rf][ks], cur[ks], acc1[rf], 0, 0, 0);

                // C col = l31 -> k; C row = (reg&3) + 8*(reg>>2) + 4*h5 -> h;
                // pair = rf*4 + w.
                #pragma unroll
                for (int rf = 0; rf < 4; ++rf)
                    #pragma unroll
                    for (int g = 0; g < 4; ++g) {
                        uint2 pk;
                        pk.x = pack2(acc1[rf][4 * g + 0], acc1[rf][4 * g + 1]);
                        pk.y = pack2(acc1[rf][4 * g + 2], acc1[rf][4 * g + 3]);
                        *(uint2*)(M + (rf * 4 + w) * 1272 + l31 * 40 + 8 * g + 4 * h5) = pk;
                    }
            }
        };

        loadbf(bfA, 0);
        int mi0 = 0, mi1 = 1;             // (2v)%3, (2v+1)%3
        for (int v = 0; v < 9; ++v) {
            step(bfA, bfB, 2 * v, mi0);
            __syncthreads();
            step(bfB, bfA, 2 * v + 1, mi1);
            __syncthreads();
            mi0 = mi0 ? mi0 - 1 : 2;      // +2 mod 3
            mi1 = mi1 ? mi1 - 1 : 2;
        }
    } else {
        // ======= CONSUMERS: 32x32 k-split stage 2 (2-tile batch) + reduce =======
        const int cw = wv - 4;            // (k,h)-slice c in [cw*256, +256)

        // wf[mt][kk]: woT row p = mt*32+l31, c = cw*256 + kk*16 + h5*8
        short8 wf[2][16];
        #pragma unroll
        for (int mt = 0; mt < 2; ++mt)
            #pragma unroll
            for (int kk = 0; kk < 16; ++kk)
                wf[mt][kk] = *(const short8*)(woT + ((size_t)(mt * 32 + l31)) * 1024 + cw * 256 + kk * 16 + h5 * 8);

        // reduce-lane mapping: 8 lanes per output column, 8 p each
        const int rc = lane >> 3;         // 0..7
        const int rp = (lane & 7) * 8;    // p base
        const int col = cw * 8 + rc;      // 0..31 = pair(0..15) x tile-parity
        const int pair = col & 15, tsel = col >> 4;
        const int orow0 = (bi * 4 + (pair >> 2)) * 256 + (pair & 3);
        const float4 boA = *(const float4*)(bo + rp);
        const float4 boB = *(const float4*)(bo + rp + 4);

        const int mpair = l31 & 15;       // stage2 B-col -> pair
        const int msel = l31 >> 4;        // stage2 B-col -> which tile of batch

        int mi0 = 0;                      // (2v)%3, updated like producers
        for (int v = 0; v < 9; ++v) {
            // ---- even slot t=2v: stage2(batch v-1) ----
            if (v >= 1) {
                const unsigned short* __restrict__ M0 = ldsM[mi0 == 2 ? 0 : mi0 + 1]; // (2v-2)%3
                const unsigned short* __restrict__ M1 = ldsM[mi0 == 0 ? 2 : mi0 - 1]; // (2v-1)%3
                const unsigned short* __restrict__ Ms = msel ? M1 : M0;
                f32x16 ac0, ac1;
                #pragma unroll
                for (int e = 0; e < 16; ++e) { ac0[e] = 0.f; ac1[e] = 0.f; }
                #pragma unroll
                for (int kk = 0; kk < 16; ++kk) {
                    const int k = cw * 8 + (kk >> 1);
                    const int h = ((kk & 1) << 4) + h5 * 8;
                    const short8 mf = *(const short8*)(Ms + mpair * 1272 + k * 40 + h);
                    ac0 = __builtin_amdgcn_mfma_f32_32x32x16_bf16(wf[0][kk], mf, ac0, 0, 0, 0);
                    ac1 = __builtin_amdgcn_mfma_f32_32x32x16_bf16(wf[1][kk], mf, ac1, 0, 0, 0);
                }
                // R[slice=cw][col=l31][p], stride 68; p = mt*32 + 8g + 4*h5 + e
                float* __restrict__ Rw = ldsR + (cw * 32 + l31) * 68;
                #pragma unroll
                for (int g = 0; g < 4; ++g) {
                    const int p0 = 8 * g + 4 * h5;
                    *(float4v*)(Rw + p0) =
                        (float4v){ac0[4 * g + 0], ac0[4 * g + 1], ac0[4 * g + 2], ac0[4 * g + 3]};
                    *(float4v*)(Rw + 32 + p0) =
                        (float4v){ac1[4 * g + 0], ac1[4 * g + 1], ac1[4 * g + 2], ac1[4 * g + 3]};
                }
            }
            __syncthreads();

            // ---- odd slot t=2v+1: reduce(batch v-1) -> out ----
            if (v >= 1) {
                const int u = v - 1;
                const float* __restrict__ Rr = ldsR + col * 68 + rp;
                float4v s0 = *(const float4v*)(Rr);
                float4v s1 = *(const float4v*)(Rr + 4);
                #pragma unroll
                for (int ks = 1; ks < 4; ++ks) {
                    s0 += *(const float4v*)(Rr + ks * 32 * 68);
                    s1 += *(const float4v*)(Rr + ks * 32 * 68 + 4);
                }
                float* __restrict__ op = out + ((size_t)(orow0 + (bj0 + 2 * u + tsel) * 4)) * 64 + rp;
                float4 o0, o1;
                o0.x = s0[0] + boA.x; o0.y = s0[1] + boA.y; o0.z = s0[2] + boA.z; o0.w = s0[3] + boA.w;
                o1.x = s1[0] + boB.x; o1.y = s1[1] + boB.y; o1.z = s1[2] + boB.z; o1.w = s1[3] + boB.w;
                *(float4*)(op) = o0;
                *(float4*)(op + 4) = o1;
            }
            __syncthreads();
            mi0 = mi0 ? mi0 - 1 : 2;      // +2 mod 3
        }
    }
}

// ---------------------------------------------------------------------------
extern "C" void kernel_launch(void* const* d_in, const int* in_sizes, int n_in,
                              void* d_out, int out_size, void* d_ws, size_t ws_size,
                              hipStream_t stream) {
    const float* msa  = (const float*)d_in[0];
    const float* ln_w = (const float*)d_in[1];
    const float* ln_b = (const float*)d_in[2];
    const float* wa   = (const float*)d_in[3];
    const float* ba   = (const float*)d_in[4];
    const float* wb   = (const float*)d_in[5];
    const float* bb   = (const float*)d_in[6];
    const float* wo   = (const float*)d_in[7];
    const float* bo   = (const float*)d_in[8];
    float* out = (float*)d_out;

    // workspace (bf16): a (1 MB) | b3 (1 MB, [octet][row] layout) | woT (128 KB)
    unsigned short* a_ws = (unsigned short*)d_ws;
    unsigned short* b_ws = a_ws + 256 * 32 * 64;
    unsigned short* woT  = b_ws + 256 * 32 * 64;

    prep<<<1024, 128, 0, stream>>>(msa, ln_w, ln_b, wa, ba, wb, bb, wo, a_ws, b_ws, woT);
    fused_opm<<<256, 512, 0, stream>>>(a_ws, b_ws, woT, bo, out);
}

// Round 4
// 97.976 us; speedup vs baseline: 1.0274x; 1.0274x over previous
//
#include <hip/hip_runtime.h>
#include <hip/hip_bf16.h>

typedef __attribute__((ext_vector_type(8))) short short8;
typedef __attribute__((ext_vector_type(4))) float float4v;
typedef __attribute__((ext_vector_type(16))) float f32x16;

__device__ __forceinline__ unsigned short f2bf(float f) {
    // round-to-nearest-even fp32 -> bf16
    unsigned int u = __builtin_bit_cast(unsigned int, f);
    unsigned int lsb = (u >> 16) & 1u;
    u += 0x7fffu + lsb;
    return (unsigned short)(u >> 16);
}

__device__ __forceinline__ unsigned int pack2(float f0, float f1) {
    // round-half-up fp32x2 -> packed bf16x2
    unsigned int u0 = __builtin_bit_cast(unsigned int, f0) + 0x8000u;
    unsigned int u1 = __builtin_bit_cast(unsigned int, f1) + 0x8000u;
    return (u0 >> 16) | (u1 & 0xffff0000u);
}

// ---------------------------------------------------------------------------
// prep (proven): LN + projections (MFMA) and woT build.
// b stored plain as b3[octet o][R=global b-row][8]: fused's 32x32 producer
// B-loads are two contiguous 512B blocks per instruction.
// ---------------------------------------------------------------------------
__global__ __launch_bounds__(128) void prep(
    const float* __restrict__ msa, const float* __restrict__ ln_w,
    const float* __restrict__ ln_b, const float* __restrict__ wa,
    const float* __restrict__ ba, const float* __restrict__ wb,
    const float* __restrict__ bb, const float* __restrict__ wo,
    unsigned short* __restrict__ a_out, unsigned short* __restrict__ b_out,
    unsigned short* __restrict__ woT)
{
    const int b = blockIdx.x;
    if (b >= 512) {                       // ---- woT transpose/convert ----
        const int idx = (b - 512) * 128 + threadIdx.x;
        const int hk = idx >> 6, p = idx & 63;
        const int h = hk >> 5, k = hk & 31;
        woT[(size_t)p * 1024 + k * 32 + h] = f2bf(wo[idx]);
        return;
    }

    __shared__ __align__(16) unsigned short xn[2][16 * 72];
    const int n = b >> 1;
    const int w = threadIdx.x >> 6;
    const int lane = threadIdx.x & 63;
    const int s0 = (b & 1) * 32 + w * 16;
    const int sl = lane >> 2, dg = lane & 3;
    const int lm = lane & 15, q = lane >> 4;

    const float* __restrict__ row = msa + ((size_t)((s0 + sl) * 256 + n)) * 64;
    float4 x[4];
    #pragma unroll
    for (int ii = 0; ii < 4; ++ii) x[ii] = *(const float4*)(row + ii * 16 + dg * 4);

    float s = 0.f;
    #pragma unroll
    for (int ii = 0; ii < 4; ++ii) s += (x[ii].x + x[ii].y) + (x[ii].z + x[ii].w);
    s += __shfl_xor(s, 1, 4);
    s += __shfl_xor(s, 2, 4);
    const float mu = s * (1.f / 64.f);

    float v = 0.f;
    #pragma unroll
    for (int ii = 0; ii < 4; ++ii) {
        float a0 = x[ii].x - mu, a1 = x[ii].y - mu, a2 = x[ii].z - mu, a3 = x[ii].w - mu;
        v += (a0 * a0 + a1 * a1) + (a2 * a2 + a3 * a3);
    }
    v += __shfl_xor(v, 1, 4);
    v += __shfl_xor(v, 2, 4);
    const float rs = rsqrtf(v * (1.f / 64.f) + 1e-5f);

    #pragma unroll
    for (int ii = 0; ii < 4; ++ii) {
        const float4 lw = *(const float4*)(ln_w + ii * 16 + dg * 4);
        const float4 lb = *(const float4*)(ln_b + ii * 16 + dg * 4);
        uint2 pk;
        pk.x = pack2((x[ii].x - mu) * rs * lw.x + lb.x, (x[ii].y - mu) * rs * lw.y + lb.y);
        pk.y = pack2((x[ii].z - mu) * rs * lw.z + lb.z, (x[ii].w - mu) * rs * lw.w + lb.w);
        *(uint2*)(&xn[w][sl * 72 + ii * 16 + dg * 4]) = pk;
    }
    __syncthreads();

    short8 afr[2];
    #pragma unroll
    for (int ks = 0; ks < 2; ++ks)
        afr[ks] = *(const short8*)(&xn[w][lm * 72 + ks * 32 + q * 8]);

    float4v acc[4];
    #pragma unroll
    for (int c = 0; c < 4; ++c) acc[c] = (float4v){0.f, 0.f, 0.f, 0.f};
    #pragma unroll
    for (int c = 0; c < 4; ++c) {
        const int hp = c * 16 + lm;
        const float* __restrict__ wsrc = (hp < 32) ? (wa + hp) : (wb + hp - 32);
        #pragma unroll
        for (int ks = 0; ks < 2; ++ks) {
            short8 bfr;
            #pragma unroll
            for (int j = 0; j < 8; ++j)
                bfr[j] = (short)f2bf(wsrc[(ks * 32 + q * 8 + j) * 32]);
            acc[c] = __builtin_amdgcn_mfma_f32_16x16x32_bf16(afr[ks], bfr, acc[c], 0, 0, 0);
        }
    }

    #pragma unroll
    for (int c = 0; c < 4; ++c) {
        const int hp = c * 16 + lm;
        const float bias = (hp < 32) ? ba[hp] : bb[hp - 32];
        const float scale = (hp < 32) ? (1.f / 64.f) : 1.f;  // fold 1/S into a
        uint2 pk;
        pk.x = pack2((acc[c][0] + bias) * scale, (acc[c][1] + bias) * scale);
        pk.y = pack2((acc[c][2] + bias) * scale, (acc[c][3] + bias) * scale);
        const int sbase = s0 + q * 4;
        if (hp < 32) {
            *(uint2*)(a_out + ((size_t)(n * 32 + hp)) * 64 + sbase) = pk;
        } else {
            // b3[o][R][8]: o = s-octet, R = global b-row; uint2 = half an octet
            const int R = n * 32 + (hp - 32);
            const int o = sbase >> 3;
            *(uint2*)(b_out + (size_t)o * 65536 + R * 8 + (sbase & 7)) = pk;
        }
    }
}

// ---------------------------------------------------------------------------
// fused_opm v12 == v10 (proven best, 98.99 us). v11 post-mortem: converting
// stage 2 to 32x32 (2-tile batch) was NEUTRAL, not a win — LDS traffic cannot
// migrate across barrier slots, and v11's even slot carried 128 KB of LDS
// (~1500 cyc) next to 1549 cyc of MFMA while the odd slot idled at ~750/516;
// per-2-tile slot-sum ~2300 cyc == v10's 2 x max(1137 MFMA, 1129 LDS) = 2274.
// v10's symmetric slots are already co-balanced between the MFMA pipe and the
// LDS pipe; deeper smoothing needs >=4-deep M (159 KB + R > 160 KB) — dead.
//   producers (waves 0-3): stage 1 at 32x32x16. wave w = all 128 A-rows x
//     B-rows [32w,+32); af[4][4] in regs; bf from plain b3 layout (two
//     contiguous 512B blocks per load), register double-buffered 1 tile ahead.
//     C: col(lane&31)=k, row=(reg&3)+8*(reg>>2)+4*(lane>>5)=h, pair=rf*4+w
//     -> M[pair][k][h] (stride 40 shorts: conflict-free 2/bank write).
//   consumers (waves 4-7): stage 2 at 16x16x32, k-split x4 — wave cw
//     contracts c in [cw*256,+256) for all 64 p; partials -> dense
//     double-buffered ldsR (float4, conflict-free), reduced 2 tiles later.
// Uniform 18-iteration loop, one barrier per slot: iter t: stage1(t) |
// stage2(t-1) | reduce(t-2). M[t] written (t), read (t+1); R[t] written
// (t+1), read (t+2) — all barrier-separated, 2-deep. LDS 111.5 KB.
// ---------------------------------------------------------------------------
__global__ __launch_bounds__(512, 2) void fused_opm(
    const unsigned short* __restrict__ a_b, const unsigned short* __restrict__ b_swz,
    const unsigned short* __restrict__ woT, const float* __restrict__ bo,
    float* __restrict__ out)
{
    __shared__ __align__(16) unsigned short ldsM[2][16 * 1272]; // 79.5 KB
    __shared__ __align__(16) float ldsR[2][4096];               // 32 KB

    const int b = blockIdx.x;
    const int bi = b >> 2;
    const int bj0 = (b & 3) << 4;        // 16 tiles per block
    const int wv = threadIdx.x >> 6;
    const int lane = threadIdx.x & 63;
    const int lm = lane & 15, q = lane >> 4;

    if (wv < 4) {
        // ========= PRODUCERS: stage 1 (32x32x16, B from plain-layout global) =========
        const int w = wv;                 // B-row slice [32w, +32)
        const int l31 = lane & 31, h5 = lane >> 5;

        short8 af[4][4];                  // [rf: row block][ks: s-step]
        #pragma unroll
        for (int rf = 0; rf < 4; ++rf)
            #pragma unroll
            for (int ks = 0; ks < 4; ++ks)
                af[rf][ks] = *(const short8*)(a_b + ((size_t)(bi * 128 + rf * 32 + l31)) * 64 + ks * 16 + h5 * 8);

        short8 bfA[4], bfB[4];            // register double-buffer, one tile ahead
        auto loadbf = [&](short8 (&dst)[4], int tt) {
            const int Rbase = (bj0 + tt) * 128 + w * 32 + l31;
            #pragma unroll
            for (int ks = 0; ks < 4; ++ks) {
                const int o = ks * 2 + h5;                // s-octet
                dst[ks] = *(const short8*)(b_swz + (size_t)o * 65536 + (size_t)Rbase * 8);
            }
        };
        auto step = [&](short8 (&cur)[4], short8 (&nxt)[4], int t) {
            if (t + 1 < 16) loadbf(nxt, t + 1);           // issue before MFMAs
            if (t < 16) {
                unsigned short* __restrict__ M = ldsM[t & 1];
                f32x16 acc1[4];
                #pragma unroll
                for (int rf = 0; rf < 4; ++rf)
                    #pragma unroll
                    for (int e = 0; e < 16; ++e) acc1[rf][e] = 0.f;
                #pragma unroll
                for (int ks = 0; ks < 4; ++ks)
                    #pragma unroll
                    for (int rf = 0; rf < 4; ++rf)
                        acc1[rf] = __builtin_amdgcn_mfma_f32_32x32x16_bf16(af[rf][ks], cur[ks], acc1[rf], 0, 0, 0);

                // C col = l31 -> k; C row = (reg&3) + 8*(reg>>2) + 4*h5 -> h;
                // i_loc = rf, j_loc = w -> pair = rf*4 + w.
                #pragma unroll
                for (int rf = 0; rf < 4; ++rf)
                    #pragma unroll
                    for (int g = 0; g < 4; ++g) {
                        uint2 pk;
                        pk.x = pack2(acc1[rf][4 * g + 0], acc1[rf][4 * g + 1]);
                        pk.y = pack2(acc1[rf][4 * g + 2], acc1[rf][4 * g + 3]);
                        *(uint2*)(M + (rf * 4 + w) * 1272 + l31 * 40 + 8 * g + 4 * h5) = pk;
                    }
            }
        };

        loadbf(bfA, 0);
        for (int t = 0; t < 18; t += 2) { // static ping-pong parity
            step(bfA, bfB, t);
            __syncthreads();              // bar(t+1)
            step(bfB, bfA, t + 1);
            __syncthreads();              // bar(t+2)
        }
    } else {
        // ============ CONSUMERS: k-split stage 2 + reduce ============
        const int cw = wv - 4;            // k-slice [cw*8, cw*8+8), reduce p-tile cw

        short8 wf[4][8];                  // woT rows p = mt*16+lm, k = cw*8+ks
        #pragma unroll
        for (int mt = 0; mt < 4; ++mt)
            #pragma unroll
            for (int ks = 0; ks < 8; ++ks)
                wf[mt][ks] = *(const short8*)(woT + ((size_t)(mt * 16 + lm)) * 1024 + (cw * 8 + ks) * 32 + q * 8);

        const float4 bo4 = *(const float4*)(bo + cw * 16 + q * 4);
        const int i = bi * 4 + (lm >> 2);
        const int jb = lm & 3;

        for (int t = 0; t < 18; ++t) {
            if (t >= 1 && t <= 16) {      // stage2(t-1): partials for tile t-1
                const int tt = t - 1;
                const unsigned short* __restrict__ M = ldsM[tt & 1];
                float4v acc2[4];
                #pragma unroll
                for (int mt = 0; mt < 4; ++mt) acc2[mt] = (float4v){0.f, 0.f, 0.f, 0.f};
                #pragma unroll
                for (int ks = 0; ks < 8; ++ks) {
                    const short8 mf = *(const short8*)(M + lm * 1272 + (cw * 8 + ks) * 40 + q * 8);
                    #pragma unroll
                    for (int mt = 0; mt < 4; ++mt)
                        acc2[mt] = __builtin_amdgcn_mfma_f32_16x16x32_bf16(wf[mt][ks], mf, acc2[mt], 0, 0, 0);
                }
                float* __restrict__ R = ldsR[tt & 1];
                #pragma unroll
                for (int mt = 0; mt < 4; ++mt)
                    *(float4v*)(&R[((cw * 4 + mt) << 8) + (lane << 2)]) = acc2[mt];
            }

            if (t >= 2) {                 // reduce(t-2): p-tile cw, all k-slices
                const int tt = t - 2;
                const float* __restrict__ R = ldsR[tt & 1];
                float4v sum = *(const float4v*)(&R[(cw << 8) + (lane << 2)]);
                #pragma unroll
                for (int kh = 1; kh < 4; ++kh)
                    sum += *(const float4v*)(&R[((kh * 4 + cw) << 8) + (lane << 2)]);
                const int j = (bj0 + tt) * 4 + jb;
                float4 o;
                o.x = sum[0] + bo4.x;
                o.y = sum[1] + bo4.y;
                o.z = sum[2] + bo4.z;
                o.w = sum[3] + bo4.w;
                *(float4*)(out + ((size_t)(i * 256 + j)) * 64 + cw * 16 + q * 4) = o;
            }
            __syncthreads();              // bar(t+1)
        }
    }
}

// ---------------------------------------------------------------------------
extern "C" void kernel_launch(void* const* d_in, const int* in_sizes, int n_in,
                              void* d_out, int out_size, void* d_ws, size_t ws_size,
                              hipStream_t stream) {
    const float* msa  = (const float*)d_in[0];
    const float* ln_w = (const float*)d_in[1];
    const float* ln_b = (const float*)d_in[2];
    const float* wa   = (const float*)d_in[3];
    const float* ba   = (const float*)d_in[4];
    const float* wb   = (const float*)d_in[5];
    const float* bb   = (const float*)d_in[6];
    const float* wo   = (const float*)d_in[7];
    const float* bo   = (const float*)d_in[8];
    float* out = (float*)d_out;

    // workspace (bf16): a (1 MB) | b3 (1 MB, [octet][row] layout) | woT (128 KB)
    unsigned short* a_ws = (unsigned short*)d_ws;
    unsigned short* b_ws = a_ws + 256 * 32 * 64;
    unsigned short* woT  = b_ws + 256 * 32 * 64;

    prep<<<1024, 128, 0, stream>>>(msa, ln_w, ln_b, wa, ba, wb, bb, wo, a_ws, b_ws, woT);
    fused_opm<<<256, 512, 0, stream>>>(a_ws, b_ws, woT, bo, out);
}